// Round 10
// baseline (222.316 us; speedup 1.0000x reference)
//
#include <hip/hip_runtime.h>
#include <hip/hip_fp16.h>

#define DIM 128
#define BKT_SHIFT 8    // 256 nodes per bucket
#define BKT_NODES 256
#define CHUNK 4096     // edges per S1/S3 block (1024-thread blocks)
#define MAXBUK 1024    // LDS histogram capacity (NBUK = ceil(N/256) must be <= this)
#define ZROW 136       // LDS z-tile row stride in halves (16B-aligned rows, free 2-way only)

typedef _Float16 half8 __attribute__((ext_vector_type(8)));
typedef float f32x4 __attribute__((ext_vector_type(4)));

// ---------------- S1: per-chunk bucket histogram (LDS atomics only) ----------------

__global__ __launch_bounds__(1024) void k_s1_hist(const int* __restrict__ ei, int* __restrict__ H,
                                                  int E, int NBUK, int NBLK) {
    __shared__ int hist[MAXBUK];
    int b = blockIdx.x, tid = threadIdx.x;
    for (int i = tid; i < NBUK; i += 1024) hist[i] = 0;
    __syncthreads();
    int e0 = b * CHUNK, e1 = min(e0 + CHUNK, E);
    for (int e = e0 + tid; e < e1; e += 1024) {
        int dst = ei[E + e];
        atomicAdd(&hist[dst >> BKT_SHIFT], 1);
    }
    __syncthreads();
    for (int k = tid; k < NBUK; k += 1024) H[(size_t)k * NBLK + b] = hist[k];
}

// ---------------- S2: scan pieces (excl(i) computed on the fly downstream) ----------------

__global__ __launch_bounds__(256) void k_scanA(const int* __restrict__ in, int* __restrict__ tmp,
                                               int* __restrict__ bsum, int n) {
    __shared__ int s[256];
    int tid = threadIdx.x;
    int i = blockIdx.x * 256 + tid;
    int v = (i < n) ? in[i] : 0;
    s[tid] = v;
    __syncthreads();
    for (int off = 1; off < 256; off <<= 1) {
        int t = (tid >= off) ? s[tid - off] : 0;
        __syncthreads();
        s[tid] += t;
        __syncthreads();
    }
    if (i < n) tmp[i] = s[tid];  // inclusive within block
    if (tid == 255) bsum[blockIdx.x] = s[255];
}

__global__ __launch_bounds__(1024) void k_scanB(int* __restrict__ bsum, int nb) {
    __shared__ int s[1024];
    int tid = threadIdx.x;
    int v = (tid < nb) ? bsum[tid] : 0;
    s[tid] = v;
    __syncthreads();
    for (int off = 1; off < 1024; off <<= 1) {
        int t = (tid >= off) ? s[tid - off] : 0;
        __syncthreads();
        s[tid] += t;
        __syncthreads();
    }
    if (tid < nb) bsum[tid] = s[tid] - v;  // exclusive block offsets
}

// excl(i) = bsum[i>>8] + tmp[i] - H[i]
__device__ __forceinline__ int h_excl(const int* H, const int* tmp, const int* bsum, int i) {
    return bsum[i >> 8] + tmp[i] - H[i];
}

// ---------------- S3: scatter edges into bucket-sorted order ----------------

__global__ __launch_bounds__(1024) void k_s3_scatter(const int* __restrict__ ei,
                                                     const int* __restrict__ H,
                                                     const int* __restrict__ tmp,
                                                     const int* __restrict__ bsum,
                                                     int* __restrict__ ssrc,
                                                     unsigned char* __restrict__ sdst, int E,
                                                     int NBUK, int NBLK) {
    __shared__ int off[MAXBUK];
    int b = blockIdx.x, tid = threadIdx.x;
    for (int k = tid; k < NBUK; k += 1024) {
        int i = k * NBLK + b;
        off[k] = h_excl(H, tmp, bsum, i);
    }
    __syncthreads();
    int e0 = b * CHUNK, e1 = min(e0 + CHUNK, E);
    for (int e = e0 + tid; e < e1; e += 1024) {
        int src = ei[e];
        int dst = ei[E + e];
        int p = atomicAdd(&off[dst >> BKT_SHIFT], 1);
        ssrc[p] = src;
        sdst[p] = (unsigned char)(dst & (BKT_NODES - 1));
    }
}

// ---------------- S4: per-bucket CSR build + deg/dinv/rp ----------------

__global__ __launch_bounds__(256) void k_s4_build(const int* __restrict__ H,
                                                  const int* __restrict__ tmp,
                                                  const int* __restrict__ bsum,
                                                  const int* __restrict__ ssrc,
                                                  const unsigned char* __restrict__ sdst,
                                                  int* __restrict__ rp, float* __restrict__ dinv,
                                                  int* __restrict__ col, int N, int E, int NBUK,
                                                  int NBLK) {
    __shared__ int cnt[BKT_NODES];
    __shared__ int pos[BKT_NODES];
    __shared__ int s[BKT_NODES];
    int bkt = blockIdx.x, tid = threadIdx.x;
    int base = h_excl(H, tmp, bsum, bkt * NBLK);
    int endv = (bkt + 1 < NBUK) ? h_excl(H, tmp, bsum, (bkt + 1) * NBLK) : E;
    int m = endv - base;
    cnt[tid] = 0;
    __syncthreads();
    for (int i = tid; i < m; i += 256) atomicAdd(&cnt[sdst[base + i]], 1);
    __syncthreads();
    int v = cnt[tid];
    s[tid] = v;
    __syncthreads();
    for (int off = 1; off < 256; off <<= 1) {
        int t = (tid >= off) ? s[tid - off] : 0;
        __syncthreads();
        s[tid] += t;
        __syncthreads();
    }
    int excl = s[tid] - v;
    pos[tid] = excl;
    int node = bkt * BKT_NODES + tid;
    if (node < N) {
        rp[node] = base + excl;
        dinv[node] = rsqrtf((float)(v + 1));  // +1: self-loop
    }
    __syncthreads();
    for (int i = tid; i < m; i += 256) {
        int r = atomicAdd(&pos[sdst[base + i]], 1);
        col[base + r] = ssrc[base + i];
    }
    if (bkt == 0 && tid == 0) rp[N] = E;
}

// ---------------- LayerNorm (+ pre-scale by dinv), fp16 output ----------------

__global__ __launch_bounds__(256) void k_ln(const float* __restrict__ x,
                                            const float* __restrict__ w,
                                            const float* __restrict__ bb,
                                            const float* __restrict__ dinv,
                                            __half2* __restrict__ u, int N) {
    int row = (blockIdx.x * 256 + threadIdx.x) >> 6;
    int lane = threadIdx.x & 63;
    if (row >= N) return;
    float2 v = *(const float2*)(x + (size_t)row * DIM + lane * 2);
    float s = v.x + v.y;
#pragma unroll
    for (int o = 32; o; o >>= 1) s += __shfl_xor(s, o, 64);
    float mu = s * (1.0f / 128.0f);
    float dx0 = v.x - mu, dx1 = v.y - mu;
    float ss = dx0 * dx0 + dx1 * dx1;
#pragma unroll
    for (int o = 32; o; o >>= 1) ss += __shfl_xor(ss, o, 64);
    float rs = rsqrtf(ss * (1.0f / 128.0f) + 1e-5f);
    float2 wv = *(const float2*)(w + lane * 2);
    float2 bv = *(const float2*)(bb + lane * 2);
    float di = dinv[row];
    float o0 = (dx0 * rs * wv.x + bv.x) * di;
    float o1 = (dx1 * rs * wv.y + bv.y) * di;
    u[(size_t)row * 64 + lane] = __floats2half2_rn(o0, o1);
}

// ---------------- hop 1: Y[i] = dinv^2 * (X[i] + sum_{e in(i)} X[src]) ----------------
// 16 nodes per block; each 16-lane group owns one node (q = feature slice of 8 halves).

__global__ __launch_bounds__(256) void k_prop(const _Float16* __restrict__ X,
                                              _Float16* __restrict__ Y,
                                              const int* __restrict__ rp,
                                              const int* __restrict__ col,
                                              const float* __restrict__ dinv, int N) {
    int tid = threadIdx.x;
    int node = blockIdx.x * 16 + (tid >> 4);
    int q = tid & 15;
    if (node >= N) return;
    const _Float16* xq = X + q * 8;
    half8 selfv = *(const half8*)(xq + (size_t)node * DIM);
    int e0 = rp[node], e1 = rp[node + 1];
    float acc[8];
#pragma unroll
    for (int f = 0; f < 8; f++) acc[f] = 0.f;
    int e = e0;
    for (; e + 7 < e1; e += 8) {
        int s0 = col[e + 0], s1 = col[e + 1], s2 = col[e + 2], s3 = col[e + 3];
        int s4 = col[e + 4], s5 = col[e + 5], s6 = col[e + 6], s7 = col[e + 7];
        half8 g0 = *(const half8*)(xq + (size_t)s0 * DIM);
        half8 g1 = *(const half8*)(xq + (size_t)s1 * DIM);
        half8 g2 = *(const half8*)(xq + (size_t)s2 * DIM);
        half8 g3 = *(const half8*)(xq + (size_t)s3 * DIM);
        half8 g4 = *(const half8*)(xq + (size_t)s4 * DIM);
        half8 g5 = *(const half8*)(xq + (size_t)s5 * DIM);
        half8 g6 = *(const half8*)(xq + (size_t)s6 * DIM);
        half8 g7 = *(const half8*)(xq + (size_t)s7 * DIM);
#pragma unroll
        for (int f = 0; f < 8; f++)
            acc[f] += (((float)g0[f] + (float)g1[f]) + ((float)g2[f] + (float)g3[f])) +
                      (((float)g4[f] + (float)g5[f]) + ((float)g6[f] + (float)g7[f]));
    }
    for (; e + 1 < e1; e += 2) {
        int s0 = col[e], s1 = col[e + 1];
        half8 g0 = *(const half8*)(xq + (size_t)s0 * DIM);
        half8 g1 = *(const half8*)(xq + (size_t)s1 * DIM);
#pragma unroll
        for (int f = 0; f < 8; f++) acc[f] += (float)g0[f] + (float)g1[f];
    }
    if (e < e1) {
        int s = col[e];
        half8 g = *(const half8*)(xq + (size_t)s * DIM);
#pragma unroll
        for (int f = 0; f < 8; f++) acc[f] += (float)g[f];
    }
    float di = dinv[node];
    float sc = di * di;
    half8 o;
#pragma unroll
    for (int f = 0; f < 8; f++) o[f] = (_Float16)(((float)selfv[f] + acc[f]) * sc);
    *(half8*)(Y + (size_t)node * DIM + q * 8) = o;
}

// ---------------- W fragment pre-pack ----------------
// pack[((tile*4+ks)*64 + lane)*8 + j] = (fp16) W[tile*16 + (lane&15)][ks*32 + 8*(lane>>4) + j]

__global__ __launch_bounds__(256) void k_packW(const float* __restrict__ W,
                                               _Float16* __restrict__ pack) {
    int t = blockIdx.x * 256 + threadIdx.x;  // 0..2047
    if (t >= 2048) return;
    int lane = t & 63, ks = (t >> 6) & 3, tile = t >> 8;
    int wrow = tile * 16 + (lane & 15);
    int wcol = ks * 32 + 8 * (lane >> 4);
    float4 w0 = *(const float4*)(W + wrow * DIM + wcol);
    float4 w1 = *(const float4*)(W + wrow * DIM + wcol + 4);
    _Float16* dst = pack + (size_t)t * 8;
    dst[0] = (_Float16)w0.x; dst[1] = (_Float16)w0.y;
    dst[2] = (_Float16)w0.z; dst[3] = (_Float16)w0.w;
    dst[4] = (_Float16)w1.x; dst[5] = (_Float16)w1.y;
    dst[6] = (_Float16)w1.z; dst[7] = (_Float16)w1.w;
}

// ---------------- fused hop 2 + matmul ----------------
// 64 nodes per block. Phase 1: 16 groups of 16 lanes pull nodes off an LDS work
// queue (dynamic balancing kills the barrier tail), compute z2 = dinv*(self+sum)
// into LDS (fp16, padded stride). Phase 2: 4 waves MFMA from LDS, write
// out = z2 @ W^T + b directly. Saves the z2 global round-trip.

__global__ __launch_bounds__(256) void k_prop_mm(const _Float16* __restrict__ X,
                                                 const int* __restrict__ rp,
                                                 const int* __restrict__ col,
                                                 const float* __restrict__ dinv,
                                                 const _Float16* __restrict__ pack,
                                                 const float* __restrict__ bias,
                                                 float* __restrict__ out, int N) {
    __shared__ _Float16 Z[64 * ZROW];
    __shared__ int ctr;
    int tid = threadIdx.x;
    if (tid == 0) ctr = 0;
    __syncthreads();
    int rB = blockIdx.x * 64;
    int q = tid & 15;  // feature slice
    const _Float16* xq = X + q * 8;
    for (;;) {
        int k = 0;
        if ((tid & 15) == 0) k = atomicAdd(&ctr, 1);
        k = __shfl(k, tid & 48, 64);  // broadcast from 16-lane-group leader
        if (k >= 64) break;
        int node = rB + k;
        half8 o;
        if (node < N) {
            half8 selfv = *(const half8*)(xq + (size_t)node * DIM);
            int e0 = rp[node], e1 = rp[node + 1];
            float acc[8];
#pragma unroll
            for (int f = 0; f < 8; f++) acc[f] = 0.f;
            int e = e0;
            for (; e + 7 < e1; e += 8) {
                int s0 = col[e + 0], s1 = col[e + 1], s2 = col[e + 2], s3 = col[e + 3];
                int s4 = col[e + 4], s5 = col[e + 5], s6 = col[e + 6], s7 = col[e + 7];
                half8 g0 = *(const half8*)(xq + (size_t)s0 * DIM);
                half8 g1 = *(const half8*)(xq + (size_t)s1 * DIM);
                half8 g2 = *(const half8*)(xq + (size_t)s2 * DIM);
                half8 g3 = *(const half8*)(xq + (size_t)s3 * DIM);
                half8 g4 = *(const half8*)(xq + (size_t)s4 * DIM);
                half8 g5 = *(const half8*)(xq + (size_t)s5 * DIM);
                half8 g6 = *(const half8*)(xq + (size_t)s6 * DIM);
                half8 g7 = *(const half8*)(xq + (size_t)s7 * DIM);
#pragma unroll
                for (int f = 0; f < 8; f++)
                    acc[f] += (((float)g0[f] + (float)g1[f]) + ((float)g2[f] + (float)g3[f])) +
                              (((float)g4[f] + (float)g5[f]) + ((float)g6[f] + (float)g7[f]));
            }
            for (; e + 1 < e1; e += 2) {
                int s0 = col[e], s1 = col[e + 1];
                half8 g0 = *(const half8*)(xq + (size_t)s0 * DIM);
                half8 g1 = *(const half8*)(xq + (size_t)s1 * DIM);
#pragma unroll
                for (int f = 0; f < 8; f++) acc[f] += (float)g0[f] + (float)g1[f];
            }
            if (e < e1) {
                int s = col[e];
                half8 gg = *(const half8*)(xq + (size_t)s * DIM);
#pragma unroll
                for (int f = 0; f < 8; f++) acc[f] += (float)gg[f];
            }
            float sc = dinv[node];
#pragma unroll
            for (int f = 0; f < 8; f++) o[f] = (_Float16)(((float)selfv[f] + acc[f]) * sc);
        } else {
#pragma unroll
            for (int f = 0; f < 8; f++) o[f] = (_Float16)0;
        }
        *(half8*)(&Z[k * ZROW + q * 8]) = o;
    }
    __syncthreads();
    // Phase 2: MFMA. Wave w handles local rows w*16..w*16+15.
    int wave = tid >> 6;
    int lane = tid & 63;
    int rw = wave * 16;
    half8 a[4];
#pragma unroll
    for (int ks = 0; ks < 4; ks++)
        a[ks] = *(const half8*)(&Z[(rw + (lane & 15)) * ZROW + ks * 32 + (lane >> 4) * 8]);
    int row0 = rB + rw + (lane >> 4) * 4;
#pragma unroll
    for (int tile = 0; tile < 8; tile++) {
        f32x4 d = {0.f, 0.f, 0.f, 0.f};
#pragma unroll
        for (int ks = 0; ks < 4; ks++) {
            half8 bf = *(const half8*)(pack + ((size_t)((tile * 4 + ks) * 64 + lane)) * 8);
            d = __builtin_amdgcn_mfma_f32_16x16x32_f16(a[ks], bf, d, 0, 0, 0);
        }
        int c = tile * 16 + (lane & 15);
        float bv = bias[c];
#pragma unroll
        for (int j = 0; j < 4; j++) {
            int rr = row0 + j;
            if (rr < N) out[(size_t)rr * DIM + c] = d[j] + bv;
        }
    }
}

// ---------------- launch ----------------

extern "C" void kernel_launch(void* const* d_in, const int* in_sizes, int n_in, void* d_out,
                              int out_size, void* d_ws, size_t ws_size, hipStream_t stream) {
    const float* x = (const float*)d_in[0];
    const int* ei = (const int*)d_in[1];
    const float* ln_w = (const float*)d_in[2];
    const float* ln_b = (const float*)d_in[3];
    const float* W = (const float*)d_in[4];
    const float* b = (const float*)d_in[5];
    float* out = (float*)d_out;

    int N = in_sizes[0] / DIM;
    int E = in_sizes[1] / 2;

    int NBUK = (N + BKT_NODES - 1) / BKT_NODES;  // 391
    int NBLK = (E + CHUNK - 1) / CHUNK;          // 391
    int M = NBUK * NBLK;                         // 152,881
    int gScan = (M + 255) / 256;                 // 598 (<= 1024)

    // workspace carve-up (all 256B-aligned)
    char* p = (char*)d_ws;
    auto carve = [&](size_t bytes) {
        void* r = (void*)p;
        p += (bytes + 255) & ~(size_t)255;
        return r;
    };
    __half* u0 = (__half*)carve((size_t)N * DIM * 2);      // 25.6 MB ping
    __half* u1 = (__half*)carve((size_t)N * DIM * 2);      // 25.6 MB pong
    _Float16* pack = (_Float16*)carve(DIM * DIM * 2);      // 32 KB packed W fragments
    int* H = (int*)carve((size_t)M * 4);                   // 600 KB bucket histograms
    float* dinv = (float*)carve((size_t)N * 4);
    int* rp = (int*)carve((size_t)(N + 1) * 4);
    int* tmp = (int*)carve((size_t)(N > M ? N : M) * 4);
    int* bsum = (int*)carve(1024 * 4);
    int* col = (int*)carve((size_t)E * 4);                 // 6.4 MB

    // sorted-edge arrays overlay u1 (dead until prop hop 1 writes it)
    int* ssrc = (int*)u1;                                  // E ints = 6.4 MB
    unsigned char* sdst = (unsigned char*)u1 + ((size_t)E * 4 + 255 & ~(size_t)255);  // E bytes

    int gW = (N + 3) / 4;     // wave-per-row kernels: 25000
    int gP = (N + 15) / 16;   // prop hop1: 16 nodes/block: 6250
    int gM = (N + 63) / 64;   // fused hop2+matmul: 64 rows/block: 1563

    k_s1_hist<<<NBLK, 1024, 0, stream>>>(ei, H, E, NBUK, NBLK);
    k_scanA<<<gScan, 256, 0, stream>>>(H, tmp, bsum, M);
    k_scanB<<<1, 1024, 0, stream>>>(bsum, gScan);
    k_s3_scatter<<<NBLK, 1024, 0, stream>>>(ei, H, tmp, bsum, ssrc, sdst, E, NBUK, NBLK);
    k_s4_build<<<NBUK, 256, 0, stream>>>(H, tmp, bsum, ssrc, sdst, rp, dinv, col, N, E, NBUK,
                                         NBLK);
    k_packW<<<8, 256, 0, stream>>>(W, pack);
    k_ln<<<gW, 256, 0, stream>>>(x, ln_w, ln_b, dinv, (__half2*)u0, N);
    // hop 1: u0 -> u1 (pre-scaled by dinv^2)   (clobbers ssrc/sdst — dead here)
    k_prop<<<gP, 256, 0, stream>>>((const _Float16*)u0, (_Float16*)u1, rp, col, dinv, N);
    // fused hop 2 + matmul: u1 -> out
    k_prop_mm<<<gM, 256, 0, stream>>>((const _Float16*)u1, rp, col, dinv, pack, b, out, N);
}

// Round 11
// 204.223 us; speedup vs baseline: 1.0886x; 1.0886x over previous
//
#include <hip/hip_runtime.h>
#include <hip/hip_fp16.h>

#define DIM 128
#define BKT_SHIFT 8    // 256 nodes per bucket
#define BKT_NODES 256
#define CHUNK 4096     // edges per S1/S3 block (1024-thread blocks)
#define MAXBUK 1024    // LDS histogram capacity (NBUK = ceil(N/256) must be <= this)
#define SRC_BITS 17    // N = 100000 < 2^17; sedge = src | (dstlow << 17)
#define SRC_MASK 0x1FFFF

typedef _Float16 half8 __attribute__((ext_vector_type(8)));
typedef float f32x4 __attribute__((ext_vector_type(4)));

// ---------------- S1: per-chunk bucket histogram (LDS atomics only) ----------------

__global__ __launch_bounds__(1024) void k_s1_hist(const int* __restrict__ ei, int* __restrict__ H,
                                                  int E, int NBUK, int NBLK) {
    __shared__ int hist[MAXBUK];
    int b = blockIdx.x, tid = threadIdx.x;
    for (int i = tid; i < NBUK; i += 1024) hist[i] = 0;
    __syncthreads();
    int e0 = b * CHUNK, e1 = min(e0 + CHUNK, E);
    for (int e = e0 + tid; e < e1; e += 1024) {
        int dst = ei[E + e];
        atomicAdd(&hist[dst >> BKT_SHIFT], 1);
    }
    __syncthreads();
    for (int k = tid; k < NBUK; k += 1024) H[(size_t)k * NBLK + b] = hist[k];
}

// ---------------- S2: scan pieces (excl(i) computed on the fly downstream) ----------------

__global__ __launch_bounds__(256) void k_scanA(const int* __restrict__ in, int* __restrict__ tmp,
                                               int* __restrict__ bsum, int n) {
    __shared__ int s[256];
    int tid = threadIdx.x;
    int i = blockIdx.x * 256 + tid;
    int v = (i < n) ? in[i] : 0;
    s[tid] = v;
    __syncthreads();
    for (int off = 1; off < 256; off <<= 1) {
        int t = (tid >= off) ? s[tid - off] : 0;
        __syncthreads();
        s[tid] += t;
        __syncthreads();
    }
    if (i < n) tmp[i] = s[tid];  // inclusive within block
    if (tid == 255) bsum[blockIdx.x] = s[255];
}

__global__ __launch_bounds__(1024) void k_scanB(int* __restrict__ bsum, int nb) {
    __shared__ int s[1024];
    int tid = threadIdx.x;
    int v = (tid < nb) ? bsum[tid] : 0;
    s[tid] = v;
    __syncthreads();
    for (int off = 1; off < 1024; off <<= 1) {
        int t = (tid >= off) ? s[tid - off] : 0;
        __syncthreads();
        s[tid] += t;
        __syncthreads();
    }
    if (tid < nb) bsum[tid] = s[tid] - v;  // exclusive block offsets
}

// excl(i) = bsum[i>>8] + tmp[i] - H[i]
__device__ __forceinline__ int h_excl(const int* H, const int* tmp, const int* bsum, int i) {
    return bsum[i >> 8] + tmp[i] - H[i];
}

// ---------------- S3: scatter edges into bucket-sorted order (packed u32) ----------------

__global__ __launch_bounds__(1024) void k_s3_scatter(const int* __restrict__ ei,
                                                     const int* __restrict__ H,
                                                     const int* __restrict__ tmp,
                                                     const int* __restrict__ bsum,
                                                     unsigned int* __restrict__ sedge, int E,
                                                     int NBUK, int NBLK) {
    __shared__ int off[MAXBUK];
    int b = blockIdx.x, tid = threadIdx.x;
    for (int k = tid; k < NBUK; k += 1024) {
        int i = k * NBLK + b;
        off[k] = h_excl(H, tmp, bsum, i);
    }
    __syncthreads();
    int e0 = b * CHUNK, e1 = min(e0 + CHUNK, E);
    for (int e = e0 + tid; e < e1; e += 1024) {
        int src = ei[e];
        int dst = ei[E + e];
        int p = atomicAdd(&off[dst >> BKT_SHIFT], 1);
        sedge[p] = (unsigned int)src | ((unsigned int)(dst & (BKT_NODES - 1)) << SRC_BITS);
    }
}

// ---------------- S4: per-bucket CSR build + deg/dinv/rp (+ packW tail blocks) ----------------
// pack[((tile*4+ks)*64 + lane)*8 + j] = (fp16) W[tile*16 + (lane&15)][ks*32 + 8*(lane>>4) + j]

__global__ __launch_bounds__(256) void k_s4_build(const int* __restrict__ H,
                                                  const int* __restrict__ tmp,
                                                  const int* __restrict__ bsum,
                                                  const unsigned int* __restrict__ sedge,
                                                  int* __restrict__ rp, float* __restrict__ dinv,
                                                  int* __restrict__ col,
                                                  const float* __restrict__ W,
                                                  _Float16* __restrict__ pack, int N, int E,
                                                  int NBUK, int NBLK) {
    int bkt = blockIdx.x, tid = threadIdx.x;
    if (bkt >= NBUK) {
        // ---- packW tail: 8 blocks x 256 threads = 2048 fragments ----
        int t = (bkt - NBUK) * 256 + tid;
        int lane = t & 63, ks = (t >> 6) & 3, tile = t >> 8;
        int wrow = tile * 16 + (lane & 15);
        int wcol = ks * 32 + 8 * (lane >> 4);
        float4 w0 = *(const float4*)(W + wrow * DIM + wcol);
        float4 w1 = *(const float4*)(W + wrow * DIM + wcol + 4);
        _Float16* dst = pack + (size_t)t * 8;
        dst[0] = (_Float16)w0.x; dst[1] = (_Float16)w0.y;
        dst[2] = (_Float16)w0.z; dst[3] = (_Float16)w0.w;
        dst[4] = (_Float16)w1.x; dst[5] = (_Float16)w1.y;
        dst[6] = (_Float16)w1.z; dst[7] = (_Float16)w1.w;
        return;
    }
    __shared__ int cnt[BKT_NODES];
    __shared__ int pos[BKT_NODES];
    __shared__ int s[BKT_NODES];
    int base = h_excl(H, tmp, bsum, bkt * NBLK);
    int endv = (bkt + 1 < NBUK) ? h_excl(H, tmp, bsum, (bkt + 1) * NBLK) : E;
    int m = endv - base;
    cnt[tid] = 0;
    __syncthreads();
    for (int i = tid; i < m; i += 256) atomicAdd(&cnt[sedge[base + i] >> SRC_BITS], 1);
    __syncthreads();
    int v = cnt[tid];
    s[tid] = v;
    __syncthreads();
    for (int off = 1; off < 256; off <<= 1) {
        int t = (tid >= off) ? s[tid - off] : 0;
        __syncthreads();
        s[tid] += t;
        __syncthreads();
    }
    int excl = s[tid] - v;
    pos[tid] = excl;
    int node = bkt * BKT_NODES + tid;
    if (node < N) {
        rp[node] = base + excl;
        dinv[node] = rsqrtf((float)(v + 1));  // +1: self-loop
    }
    __syncthreads();
    for (int i = tid; i < m; i += 256) {
        unsigned int ev = sedge[base + i];
        int r = atomicAdd(&pos[ev >> SRC_BITS], 1);
        col[base + r] = (int)(ev & SRC_MASK);
    }
    if (bkt == 0 && tid == 0) rp[N] = E;
}

// ---------------- LayerNorm (+ pre-scale by dinv), fp16 output ----------------

__global__ __launch_bounds__(256) void k_ln(const float* __restrict__ x,
                                            const float* __restrict__ w,
                                            const float* __restrict__ bb,
                                            const float* __restrict__ dinv,
                                            __half2* __restrict__ u, int N) {
    int row = (blockIdx.x * 256 + threadIdx.x) >> 6;
    int lane = threadIdx.x & 63;
    if (row >= N) return;
    float2 v = *(const float2*)(x + (size_t)row * DIM + lane * 2);
    float s = v.x + v.y;
#pragma unroll
    for (int o = 32; o; o >>= 1) s += __shfl_xor(s, o, 64);
    float mu = s * (1.0f / 128.0f);
    float dx0 = v.x - mu, dx1 = v.y - mu;
    float ss = dx0 * dx0 + dx1 * dx1;
#pragma unroll
    for (int o = 32; o; o >>= 1) ss += __shfl_xor(ss, o, 64);
    float rs = rsqrtf(ss * (1.0f / 128.0f) + 1e-5f);
    float2 wv = *(const float2*)(w + lane * 2);
    float2 bv = *(const float2*)(bb + lane * 2);
    float di = dinv[row];
    float o0 = (dx0 * rs * wv.x + bv.x) * di;
    float o1 = (dx1 * rs * wv.y + bv.y) * di;
    u[(size_t)row * 64 + lane] = __floats2half2_rn(o0, o1);
}

// ---------------- propagate: Y[i] = scale * (X[i] + sum_{e in(i)} X[src]) ----------------
// 16 nodes per block; each 16-lane group owns one node (q = feature slice of 8 halves).
// 8-deep edge unroll -> up to 32 independent row-gathers in flight per wave.

__global__ __launch_bounds__(256) void k_prop(const _Float16* __restrict__ X,
                                              _Float16* __restrict__ Y,
                                              const int* __restrict__ rp,
                                              const int* __restrict__ col,
                                              const float* __restrict__ dinv, int N, int squared) {
    int tid = threadIdx.x;
    int node = blockIdx.x * 16 + (tid >> 4);
    int q = tid & 15;
    if (node >= N) return;
    const _Float16* xq = X + q * 8;
    half8 selfv = *(const half8*)(xq + (size_t)node * DIM);
    int e0 = rp[node], e1 = rp[node + 1];
    float acc[8];
#pragma unroll
    for (int f = 0; f < 8; f++) acc[f] = 0.f;
    int e = e0;
    for (; e + 7 < e1; e += 8) {
        int s0 = col[e + 0], s1 = col[e + 1], s2 = col[e + 2], s3 = col[e + 3];
        int s4 = col[e + 4], s5 = col[e + 5], s6 = col[e + 6], s7 = col[e + 7];
        half8 g0 = *(const half8*)(xq + (size_t)s0 * DIM);
        half8 g1 = *(const half8*)(xq + (size_t)s1 * DIM);
        half8 g2 = *(const half8*)(xq + (size_t)s2 * DIM);
        half8 g3 = *(const half8*)(xq + (size_t)s3 * DIM);
        half8 g4 = *(const half8*)(xq + (size_t)s4 * DIM);
        half8 g5 = *(const half8*)(xq + (size_t)s5 * DIM);
        half8 g6 = *(const half8*)(xq + (size_t)s6 * DIM);
        half8 g7 = *(const half8*)(xq + (size_t)s7 * DIM);
#pragma unroll
        for (int f = 0; f < 8; f++)
            acc[f] += (((float)g0[f] + (float)g1[f]) + ((float)g2[f] + (float)g3[f])) +
                      (((float)g4[f] + (float)g5[f]) + ((float)g6[f] + (float)g7[f]));
    }
    for (; e + 1 < e1; e += 2) {
        int s0 = col[e], s1 = col[e + 1];
        half8 g0 = *(const half8*)(xq + (size_t)s0 * DIM);
        half8 g1 = *(const half8*)(xq + (size_t)s1 * DIM);
#pragma unroll
        for (int f = 0; f < 8; f++) acc[f] += (float)g0[f] + (float)g1[f];
    }
    if (e < e1) {
        int s = col[e];
        half8 g = *(const half8*)(xq + (size_t)s * DIM);
#pragma unroll
        for (int f = 0; f < 8; f++) acc[f] += (float)g[f];
    }
    float di = dinv[node];
    float sc = squared ? di * di : di;
    half8 o;
#pragma unroll
    for (int f = 0; f < 8; f++) o[f] = (_Float16)(((float)selfv[f] + acc[f]) * sc);
    *(half8*)(Y + (size_t)node * DIM + q * 8) = o;
}

// ---------------- MFMA tall-skinny matmul ----------------
// 4 waves/block, 16 rows per wave, 64 rows/block. A from global, B from pack (L2-hot).

__global__ __launch_bounds__(256) void k_mm(const _Float16* __restrict__ Z,
                                            const _Float16* __restrict__ pack,
                                            const float* __restrict__ bias,
                                            float* __restrict__ out, int N) {
    int wave = threadIdx.x >> 6;
    int lane = threadIdx.x & 63;
    int rB = blockIdx.x * 64 + wave * 16;
    int r = rB + (lane & 15);
    bool rok = (r < N);
    half8 a[4];
    if (rok) {
        const _Float16* zr = Z + (size_t)r * DIM + 8 * (lane >> 4);
#pragma unroll
        for (int ks = 0; ks < 4; ks++) a[ks] = *(const half8*)(zr + ks * 32);
    } else {
#pragma unroll
        for (int ks = 0; ks < 4; ks++)
#pragma unroll
            for (int j = 0; j < 8; j++) a[ks][j] = (_Float16)0;
    }
    int row0 = rB + (lane >> 4) * 4;
#pragma unroll
    for (int tile = 0; tile < 8; tile++) {
        f32x4 d = {0.f, 0.f, 0.f, 0.f};
#pragma unroll
        for (int ks = 0; ks < 4; ks++) {
            half8 bf = *(const half8*)(pack + ((size_t)((tile * 4 + ks) * 64 + lane)) * 8);
            d = __builtin_amdgcn_mfma_f32_16x16x32_f16(a[ks], bf, d, 0, 0, 0);
        }
        int c = tile * 16 + (lane & 15);
        float bv = bias[c];
#pragma unroll
        for (int j = 0; j < 4; j++) {
            int rr = row0 + j;
            if (rr < N) out[(size_t)rr * DIM + c] = d[j] + bv;
        }
    }
}

// ---------------- launch ----------------

extern "C" void kernel_launch(void* const* d_in, const int* in_sizes, int n_in, void* d_out,
                              int out_size, void* d_ws, size_t ws_size, hipStream_t stream) {
    const float* x = (const float*)d_in[0];
    const int* ei = (const int*)d_in[1];
    const float* ln_w = (const float*)d_in[2];
    const float* ln_b = (const float*)d_in[3];
    const float* W = (const float*)d_in[4];
    const float* b = (const float*)d_in[5];
    float* out = (float*)d_out;

    int N = in_sizes[0] / DIM;
    int E = in_sizes[1] / 2;

    int NBUK = (N + BKT_NODES - 1) / BKT_NODES;  // 391
    int NBLK = (E + CHUNK - 1) / CHUNK;          // 391
    int M = NBUK * NBLK;                         // 152,881
    int gScan = (M + 255) / 256;                 // 598 (<= 1024)

    // workspace carve-up (all 256B-aligned)
    char* p = (char*)d_ws;
    auto carve = [&](size_t bytes) {
        void* r = (void*)p;
        p += (bytes + 255) & ~(size_t)255;
        return r;
    };
    __half* u0 = (__half*)carve((size_t)N * DIM * 2);      // 25.6 MB ping
    __half* u1 = (__half*)carve((size_t)N * DIM * 2);      // 25.6 MB pong
    _Float16* pack = (_Float16*)carve(DIM * DIM * 2);      // 32 KB packed W fragments
    int* H = (int*)carve((size_t)M * 4);                   // 600 KB bucket histograms
    float* dinv = (float*)carve((size_t)N * 4);
    int* rp = (int*)carve((size_t)(N + 1) * 4);
    int* tmp = (int*)carve((size_t)(N > M ? N : M) * 4);
    int* bsum = (int*)carve(1024 * 4);
    int* col = (int*)carve((size_t)E * 4);                 // 6.4 MB

    // sorted-edge array overlays u1 (dead until prop hop 1 writes it)
    unsigned int* sedge = (unsigned int*)u1;               // E u32 = 6.4 MB

    int gW = (N + 3) / 4;     // wave-per-row kernels: 25000
    int gP = (N + 15) / 16;   // prop: 16 nodes/block: 6250
    int gM = (N + 63) / 64;   // matmul row blocks: 1563

    k_s1_hist<<<NBLK, 1024, 0, stream>>>(ei, H, E, NBUK, NBLK);
    k_scanA<<<gScan, 256, 0, stream>>>(H, tmp, bsum, M);
    k_scanB<<<1, 1024, 0, stream>>>(bsum, gScan);
    k_s3_scatter<<<NBLK, 1024, 0, stream>>>(ei, H, tmp, bsum, sedge, E, NBUK, NBLK);
    // S4 (+8 tail blocks doing the W fragment pre-pack)
    k_s4_build<<<NBUK + 8, 256, 0, stream>>>(H, tmp, bsum, sedge, rp, dinv, col, W, pack, N, E,
                                             NBUK, NBLK);
    k_ln<<<gW, 256, 0, stream>>>(x, ln_w, ln_b, dinv, (__half2*)u0, N);
    // hop 1: u0 -> u1 (pre-scaled by dinv^2)   (clobbers sedge — dead here)
    k_prop<<<gP, 256, 0, stream>>>((const _Float16*)u0, (_Float16*)u1, rp, col, dinv, N, 1);
    // hop 2: u1 -> u0 (scaled by dinv)
    k_prop<<<gP, 256, 0, stream>>>((const _Float16*)u1, (_Float16*)u0, rp, col, dinv, N, 0);
    // out = z2 @ W^T + b  (MFMA fp16, fp32 accumulate)
    k_mm<<<gM, 256, 0, stream>>>((const _Float16*)u0, pack, b, out, N);
}

// Round 12
// 200.908 us; speedup vs baseline: 1.1066x; 1.0165x over previous
//
#include <hip/hip_runtime.h>
#include <hip/hip_fp16.h>

#define DIM 128
#define BKT_SHIFT 8    // 256 nodes per bucket
#define BKT_NODES 256
#define CHUNK 8192     // edges per S1/S3 block (1024 threads x 8 edges)
#define MAXBUK 1024    // LDS histogram capacity (NBUK = ceil(N/256) must be <= this)
#define SRC_BITS 17    // N = 100000 < 2^17; sedge = src | (dstlow << 17)
#define SRC_MASK 0x1FFFF
#define S4CAP 5120     // LDS staging capacity for one bucket's edges (mean ~4092)

typedef _Float16 half8 __attribute__((ext_vector_type(8)));
typedef float f32x4 __attribute__((ext_vector_type(4)));

// ---------------- S1: per-chunk bucket histogram (LDS atomics, int4 edge reads) -------------

__global__ __launch_bounds__(1024) void k_s1_hist(const int* __restrict__ ei, int* __restrict__ H,
                                                  int E, int NBUK, int NBLK) {
    __shared__ int hist[MAXBUK];
    int b = blockIdx.x, tid = threadIdx.x;
    for (int i = tid; i < NBUK; i += 1024) hist[i] = 0;
    __syncthreads();
    int e0 = b * CHUNK + tid * 8;
    int e1 = min(b * CHUNK + CHUNK, E);
    if (e0 + 7 < e1) {
        int4 d0 = *(const int4*)(ei + E + e0);
        int4 d1 = *(const int4*)(ei + E + e0 + 4);
        atomicAdd(&hist[d0.x >> BKT_SHIFT], 1);
        atomicAdd(&hist[d0.y >> BKT_SHIFT], 1);
        atomicAdd(&hist[d0.z >> BKT_SHIFT], 1);
        atomicAdd(&hist[d0.w >> BKT_SHIFT], 1);
        atomicAdd(&hist[d1.x >> BKT_SHIFT], 1);
        atomicAdd(&hist[d1.y >> BKT_SHIFT], 1);
        atomicAdd(&hist[d1.z >> BKT_SHIFT], 1);
        atomicAdd(&hist[d1.w >> BKT_SHIFT], 1);
    } else {
        for (int e = e0; e < e1; ++e) atomicAdd(&hist[ei[E + e] >> BKT_SHIFT], 1);
    }
    __syncthreads();
    for (int k = tid; k < NBUK; k += 1024) H[(size_t)k * NBLK + b] = hist[k];
}

// ---------------- S2: scan pieces (excl(i) computed on the fly downstream) ----------------

__global__ __launch_bounds__(256) void k_scanA(const int* __restrict__ in, int* __restrict__ tmp,
                                               int* __restrict__ bsum, int n) {
    __shared__ int s[256];
    int tid = threadIdx.x;
    int i = blockIdx.x * 256 + tid;
    int v = (i < n) ? in[i] : 0;
    s[tid] = v;
    __syncthreads();
    for (int off = 1; off < 256; off <<= 1) {
        int t = (tid >= off) ? s[tid - off] : 0;
        __syncthreads();
        s[tid] += t;
        __syncthreads();
    }
    if (i < n) tmp[i] = s[tid];  // inclusive within block
    if (tid == 255) bsum[blockIdx.x] = s[255];
}

__global__ __launch_bounds__(1024) void k_scanB(int* __restrict__ bsum, int nb) {
    __shared__ int s[1024];
    int tid = threadIdx.x;
    int v = (tid < nb) ? bsum[tid] : 0;
    s[tid] = v;
    __syncthreads();
    for (int off = 1; off < 1024; off <<= 1) {
        int t = (tid >= off) ? s[tid - off] : 0;
        __syncthreads();
        s[tid] += t;
        __syncthreads();
    }
    if (tid < nb) bsum[tid] = s[tid] - v;  // exclusive block offsets
}

// excl(i) = bsum[i>>8] + tmp[i] - H[i]
__device__ __forceinline__ int h_excl(const int* H, const int* tmp, const int* bsum, int i) {
    return bsum[i >> 8] + tmp[i] - H[i];
}

// ---------------- S3: scatter edges into bucket-sorted order (packed u32) ----------------

__device__ __forceinline__ void s3_one(int src, int dst, int* off, unsigned int* sedge) {
    int p = atomicAdd(&off[dst >> BKT_SHIFT], 1);
    sedge[p] = (unsigned int)src | ((unsigned int)(dst & (BKT_NODES - 1)) << SRC_BITS);
}

__global__ __launch_bounds__(1024) void k_s3_scatter(const int* __restrict__ ei,
                                                     const int* __restrict__ H,
                                                     const int* __restrict__ tmp,
                                                     const int* __restrict__ bsum,
                                                     unsigned int* __restrict__ sedge, int E,
                                                     int NBUK, int NBLK) {
    __shared__ int off[MAXBUK];
    int b = blockIdx.x, tid = threadIdx.x;
    for (int k = tid; k < NBUK; k += 1024) {
        int i = k * NBLK + b;
        off[k] = h_excl(H, tmp, bsum, i);
    }
    __syncthreads();
    int e0 = b * CHUNK + tid * 8;
    int e1 = min(b * CHUNK + CHUNK, E);
    if (e0 + 7 < e1) {
        int4 s0 = *(const int4*)(ei + e0);
        int4 s1 = *(const int4*)(ei + e0 + 4);
        int4 d0 = *(const int4*)(ei + E + e0);
        int4 d1 = *(const int4*)(ei + E + e0 + 4);
        s3_one(s0.x, d0.x, off, sedge);
        s3_one(s0.y, d0.y, off, sedge);
        s3_one(s0.z, d0.z, off, sedge);
        s3_one(s0.w, d0.w, off, sedge);
        s3_one(s1.x, d1.x, off, sedge);
        s3_one(s1.y, d1.y, off, sedge);
        s3_one(s1.z, d1.z, off, sedge);
        s3_one(s1.w, d1.w, off, sedge);
    } else {
        for (int e = e0; e < e1; ++e) s3_one(ei[e], ei[E + e], off, sedge);
    }
}

// ---------------- S4: per-bucket CSR build + deg/dinv/rp (+ packW tail blocks) ----------------
// Stages the bucket's sedge slice in LDS (read twice: count + scatter).
// pack[((tile*4+ks)*64 + lane)*8 + j] = (fp16) W[tile*16 + (lane&15)][ks*32 + 8*(lane>>4) + j]

__global__ __launch_bounds__(256) void k_s4_build(const int* __restrict__ H,
                                                  const int* __restrict__ tmp,
                                                  const int* __restrict__ bsum,
                                                  const unsigned int* __restrict__ sedge,
                                                  int* __restrict__ rp, float* __restrict__ dinv,
                                                  int* __restrict__ col,
                                                  const float* __restrict__ W,
                                                  _Float16* __restrict__ pack, int N, int E,
                                                  int NBUK, int NBLK) {
    int bkt = blockIdx.x, tid = threadIdx.x;
    if (bkt >= NBUK) {
        // ---- packW tail: 8 blocks x 256 threads = 2048 fragments ----
        int t = (bkt - NBUK) * 256 + tid;
        int lane = t & 63, ks = (t >> 6) & 3, tile = t >> 8;
        int wrow = tile * 16 + (lane & 15);
        int wcol = ks * 32 + 8 * (lane >> 4);
        float4 w0 = *(const float4*)(W + wrow * DIM + wcol);
        float4 w1 = *(const float4*)(W + wrow * DIM + wcol + 4);
        _Float16* dst = pack + (size_t)t * 8;
        dst[0] = (_Float16)w0.x; dst[1] = (_Float16)w0.y;
        dst[2] = (_Float16)w0.z; dst[3] = (_Float16)w0.w;
        dst[4] = (_Float16)w1.x; dst[5] = (_Float16)w1.y;
        dst[6] = (_Float16)w1.z; dst[7] = (_Float16)w1.w;
        return;
    }
    __shared__ int cnt[BKT_NODES];
    __shared__ int pos[BKT_NODES];
    __shared__ int s[BKT_NODES];
    __shared__ unsigned int se[S4CAP];
    int base = h_excl(H, tmp, bsum, bkt * NBLK);
    int endv = (bkt + 1 < NBUK) ? h_excl(H, tmp, bsum, (bkt + 1) * NBLK) : E;
    int m = endv - base;
    bool fits = (m <= S4CAP);
    cnt[tid] = 0;
    if (fits)
        for (int i = tid; i < m; i += 256) se[i] = sedge[base + i];
    __syncthreads();
    if (fits) {
        for (int i = tid; i < m; i += 256) atomicAdd(&cnt[se[i] >> SRC_BITS], 1);
    } else {
        for (int i = tid; i < m; i += 256) atomicAdd(&cnt[sedge[base + i] >> SRC_BITS], 1);
    }
    __syncthreads();
    int v = cnt[tid];
    s[tid] = v;
    __syncthreads();
    for (int off = 1; off < 256; off <<= 1) {
        int t = (tid >= off) ? s[tid - off] : 0;
        __syncthreads();
        s[tid] += t;
        __syncthreads();
    }
    int excl = s[tid] - v;
    pos[tid] = excl;
    int node = bkt * BKT_NODES + tid;
    if (node < N) {
        rp[node] = base + excl;
        dinv[node] = rsqrtf((float)(v + 1));  // +1: self-loop
    }
    __syncthreads();
    if (fits) {
        for (int i = tid; i < m; i += 256) {
            unsigned int ev = se[i];
            int r = atomicAdd(&pos[ev >> SRC_BITS], 1);
            col[base + r] = (int)(ev & SRC_MASK);
        }
    } else {
        for (int i = tid; i < m; i += 256) {
            unsigned int ev = sedge[base + i];
            int r = atomicAdd(&pos[ev >> SRC_BITS], 1);
            col[base + r] = (int)(ev & SRC_MASK);
        }
    }
    if (bkt == 0 && tid == 0) rp[N] = E;
}

// ---------------- LayerNorm (+ pre-scale by dinv), fp16 output ----------------

__global__ __launch_bounds__(256) void k_ln(const float* __restrict__ x,
                                            const float* __restrict__ w,
                                            const float* __restrict__ bb,
                                            const float* __restrict__ dinv,
                                            __half2* __restrict__ u, int N) {
    int row = (blockIdx.x * 256 + threadIdx.x) >> 6;
    int lane = threadIdx.x & 63;
    if (row >= N) return;
    float2 v = *(const float2*)(x + (size_t)row * DIM + lane * 2);
    float s = v.x + v.y;
#pragma unroll
    for (int o = 32; o; o >>= 1) s += __shfl_xor(s, o, 64);
    float mu = s * (1.0f / 128.0f);
    float dx0 = v.x - mu, dx1 = v.y - mu;
    float ss = dx0 * dx0 + dx1 * dx1;
#pragma unroll
    for (int o = 32; o; o >>= 1) ss += __shfl_xor(ss, o, 64);
    float rs = rsqrtf(ss * (1.0f / 128.0f) + 1e-5f);
    float2 wv = *(const float2*)(w + lane * 2);
    float2 bv = *(const float2*)(bb + lane * 2);
    float di = dinv[row];
    float o0 = (dx0 * rs * wv.x + bv.x) * di;
    float o1 = (dx1 * rs * wv.y + bv.y) * di;
    u[(size_t)row * 64 + lane] = __floats2half2_rn(o0, o1);
}

// ---------------- propagate: Y[i] = scale * (X[i] + sum_{e in(i)} X[src]) ----------------
// 16 nodes per block; each 16-lane group owns one node (q = feature slice of 8 halves).
// 8-deep edge unroll -> up to 32 independent row-gathers in flight per wave.

__global__ __launch_bounds__(256) void k_prop(const _Float16* __restrict__ X,
                                              _Float16* __restrict__ Y,
                                              const int* __restrict__ rp,
                                              const int* __restrict__ col,
                                              const float* __restrict__ dinv, int N, int squared) {
    int tid = threadIdx.x;
    int node = blockIdx.x * 16 + (tid >> 4);
    int q = tid & 15;
    if (node >= N) return;
    const _Float16* xq = X + q * 8;
    half8 selfv = *(const half8*)(xq + (size_t)node * DIM);
    int e0 = rp[node], e1 = rp[node + 1];
    float acc[8];
#pragma unroll
    for (int f = 0; f < 8; f++) acc[f] = 0.f;
    int e = e0;
    for (; e + 7 < e1; e += 8) {
        int s0 = col[e + 0], s1 = col[e + 1], s2 = col[e + 2], s3 = col[e + 3];
        int s4 = col[e + 4], s5 = col[e + 5], s6 = col[e + 6], s7 = col[e + 7];
        half8 g0 = *(const half8*)(xq + (size_t)s0 * DIM);
        half8 g1 = *(const half8*)(xq + (size_t)s1 * DIM);
        half8 g2 = *(const half8*)(xq + (size_t)s2 * DIM);
        half8 g3 = *(const half8*)(xq + (size_t)s3 * DIM);
        half8 g4 = *(const half8*)(xq + (size_t)s4 * DIM);
        half8 g5 = *(const half8*)(xq + (size_t)s5 * DIM);
        half8 g6 = *(const half8*)(xq + (size_t)s6 * DIM);
        half8 g7 = *(const half8*)(xq + (size_t)s7 * DIM);
#pragma unroll
        for (int f = 0; f < 8; f++)
            acc[f] += (((float)g0[f] + (float)g1[f]) + ((float)g2[f] + (float)g3[f])) +
                      (((float)g4[f] + (float)g5[f]) + ((float)g6[f] + (float)g7[f]));
    }
    for (; e + 1 < e1; e += 2) {
        int s0 = col[e], s1 = col[e + 1];
        half8 g0 = *(const half8*)(xq + (size_t)s0 * DIM);
        half8 g1 = *(const half8*)(xq + (size_t)s1 * DIM);
#pragma unroll
        for (int f = 0; f < 8; f++) acc[f] += (float)g0[f] + (float)g1[f];
    }
    if (e < e1) {
        int s = col[e];
        half8 g = *(const half8*)(xq + (size_t)s * DIM);
#pragma unroll
        for (int f = 0; f < 8; f++) acc[f] += (float)g[f];
    }
    float di = dinv[node];
    float sc = squared ? di * di : di;
    half8 o;
#pragma unroll
    for (int f = 0; f < 8; f++) o[f] = (_Float16)(((float)selfv[f] + acc[f]) * sc);
    *(half8*)(Y + (size_t)node * DIM + q * 8) = o;
}

// ---------------- MFMA tall-skinny matmul ----------------
// 4 waves/block, 16 rows per wave, 64 rows/block. A from global, B from pack (L2-hot).

__global__ __launch_bounds__(256) void k_mm(const _Float16* __restrict__ Z,
                                            const _Float16* __restrict__ pack,
                                            const float* __restrict__ bias,
                                            float* __restrict__ out, int N) {
    int wave = threadIdx.x >> 6;
    int lane = threadIdx.x & 63;
    int rB = blockIdx.x * 64 + wave * 16;
    int r = rB + (lane & 15);
    bool rok = (r < N);
    half8 a[4];
    if (rok) {
        const _Float16* zr = Z + (size_t)r * DIM + 8 * (lane >> 4);
#pragma unroll
        for (int ks = 0; ks < 4; ks++) a[ks] = *(const half8*)(zr + ks * 32);
    } else {
#pragma unroll
        for (int ks = 0; ks < 4; ks++)
#pragma unroll
            for (int j = 0; j < 8; j++) a[ks][j] = (_Float16)0;
    }
    int row0 = rB + (lane >> 4) * 4;
#pragma unroll
    for (int tile = 0; tile < 8; tile++) {
        f32x4 d = {0.f, 0.f, 0.f, 0.f};
#pragma unroll
        for (int ks = 0; ks < 4; ks++) {
            half8 bf = *(const half8*)(pack + ((size_t)((tile * 4 + ks) * 64 + lane)) * 8);
            d = __builtin_amdgcn_mfma_f32_16x16x32_f16(a[ks], bf, d, 0, 0, 0);
        }
        int c = tile * 16 + (lane & 15);
        float bv = bias[c];
#pragma unroll
        for (int j = 0; j < 4; j++) {
            int rr = row0 + j;
            if (rr < N) out[(size_t)rr * DIM + c] = d[j] + bv;
        }
    }
}

// ---------------- launch ----------------

extern "C" void kernel_launch(void* const* d_in, const int* in_sizes, int n_in, void* d_out,
                              int out_size, void* d_ws, size_t ws_size, hipStream_t stream) {
    const float* x = (const float*)d_in[0];
    const int* ei = (const int*)d_in[1];
    const float* ln_w = (const float*)d_in[2];
    const float* ln_b = (const float*)d_in[3];
    const float* W = (const float*)d_in[4];
    const float* b = (const float*)d_in[5];
    float* out = (float*)d_out;

    int N = in_sizes[0] / DIM;
    int E = in_sizes[1] / 2;

    int NBUK = (N + BKT_NODES - 1) / BKT_NODES;  // 391
    int NBLK = (E + CHUNK - 1) / CHUNK;          // 196
    int M = NBUK * NBLK;                         // 76,636
    int gScan = (M + 255) / 256;                 // 300 (<= 1024)

    // workspace carve-up (all 256B-aligned)
    char* p = (char*)d_ws;
    auto carve = [&](size_t bytes) {
        void* r = (void*)p;
        p += (bytes + 255) & ~(size_t)255;
        return r;
    };
    __half* u0 = (__half*)carve((size_t)N * DIM * 2);      // 25.6 MB ping
    __half* u1 = (__half*)carve((size_t)N * DIM * 2);      // 25.6 MB pong
    _Float16* pack = (_Float16*)carve(DIM * DIM * 2);      // 32 KB packed W fragments
    int* H = (int*)carve((size_t)M * 4);                   // 306 KB bucket histograms
    float* dinv = (float*)carve((size_t)N * 4);
    int* rp = (int*)carve((size_t)(N + 1) * 4);
    int* tmp = (int*)carve((size_t)(N > M ? N : M) * 4);
    int* bsum = (int*)carve(1024 * 4);
    int* col = (int*)carve((size_t)E * 4);                 // 6.4 MB

    // sorted-edge array overlays u1 (dead until prop hop 1 writes it)
    unsigned int* sedge = (unsigned int*)u1;               // E u32 = 6.4 MB

    int gW = (N + 3) / 4;     // wave-per-row kernels: 25000
    int gP = (N + 15) / 16;   // prop: 16 nodes/block: 6250
    int gM = (N + 63) / 64;   // matmul row blocks: 1563

    k_s1_hist<<<NBLK, 1024, 0, stream>>>(ei, H, E, NBUK, NBLK);
    k_scanA<<<gScan, 256, 0, stream>>>(H, tmp, bsum, M);
    k_scanB<<<1, 1024, 0, stream>>>(bsum, gScan);
    k_s3_scatter<<<NBLK, 1024, 0, stream>>>(ei, H, tmp, bsum, sedge, E, NBUK, NBLK);
    // S4 (+8 tail blocks doing the W fragment pre-pack)
    k_s4_build<<<NBUK + 8, 256, 0, stream>>>(H, tmp, bsum, sedge, rp, dinv, col, W, pack, N, E,
                                             NBUK, NBLK);
    k_ln<<<gW, 256, 0, stream>>>(x, ln_w, ln_b, dinv, (__half2*)u0, N);
    // hop 1: u0 -> u1 (pre-scaled by dinv^2)   (clobbers sedge — dead here)
    k_prop<<<gP, 256, 0, stream>>>((const _Float16*)u0, (_Float16*)u1, rp, col, dinv, N, 1);
    // hop 2: u1 -> u0 (scaled by dinv)
    k_prop<<<gP, 256, 0, stream>>>((const _Float16*)u1, (_Float16*)u0, rp, col, dinv, N, 0);
    // out = z2 @ W^T + b  (MFMA fp16, fp32 accumulate)
    k_mm<<<gM, 256, 0, stream>>>((const _Float16*)u0, pack, b, out, N);
}